// Round 1
// baseline (5838.691 us; speedup 1.0000x reference)
//
#include <hip/hip_runtime.h>

// TimeLSTM persistent-scan kernel for MI355X (gfx950), round 4.
// Grid: 128 blocks x 320 threads. grp = blockIdx&3 owns batches grp*16..+15;
// member = blockIdx>>2 owns columns member*16..+15 of each gate and of W_d.
// Weights live in VGPRs as f16 MFMA B-fragments for all 1024 steps.
//
// Round-4 change: tag-in-data exchange protocol. Each published (b,col) is a
// single 64-bit atomic qword {tag=t+1 (hi32), packed f16 h,c (lo32)} — every
// word is self-validating, so the flag round trip, the pre-flag vmcnt-drain
// barrier, and the separate gather RT all disappear. Consumers spin-load
// their slice qwords directly (predicated per-qword retry) and unpack once
// all tags match. Monotone tags + 2-phase buffering make stale/poisoned
// reads harmless (equality check), so no workspace memset is needed either.
// Per-step serialized MALL hops: ~4 -> ~2; barriers/step: 3 -> 2.

typedef _Float16 f16;
typedef _Float16 f16x8 __attribute__((ext_vector_type(8)));
typedef float f32x4 __attribute__((ext_vector_type(4)));

#define S_ 1024
#define IN_ 256
#define H_ 512
#define ECONST 2.718281828459045f

__device__ __forceinline__ float sigf(float x) { return 1.0f / (1.0f + __expf(-x)); }
__device__ __forceinline__ float tanh_f(float x) { return 1.0f - 2.0f / (__expf(2.0f * x) + 1.0f); }

__device__ __forceinline__ unsigned int pack_hc(float h, float c) {
    union { f16 f; unsigned short u; } ph, pc;
    ph.f = (f16)h; pc.f = (f16)c;
    return ((unsigned int)pc.u << 16) | (unsigned int)ph.u;
}

__launch_bounds__(320, 2)
__global__ void tlstm_scan(
    const float* __restrict__ inputs, const float* __restrict__ tstamps,
    const int* __restrict__ lens,
    const float* __restrict__ W_all, const float* __restrict__ b_all,
    const float* __restrict__ U_all, const float* __restrict__ b_u,
    const float* __restrict__ W_d, const float* __restrict__ b_d,
    float* __restrict__ out0, float* __restrict__ out1, float* __restrict__ out2,
    unsigned long long* __restrict__ hcbuf)
{
    __shared__ __align__(16) f16 A_sm[96 * 16 * 8];   // 24 KB  (h: kb0..63, x: kb64..95)
    __shared__ __align__(16) f16 C_sm[64 * 16 * 8];   // 16 KB  (c operand)
    __shared__ float outs_sm[5 * 16 * 17];            // +1 pad on col
    __shared__ float c_loc[16 * 16];                  // fp32 c state (own cells)
    __shared__ float bias_sm[5 * 16];
    __shared__ int   len_sm[16];

    const int tid    = threadIdx.x;
    const int grp    = blockIdx.x & 3;
    const int member = blockIdx.x >> 2;
    const int wave   = tid >> 6;
    const int lane   = tid & 63;
    const int q      = lane >> 4;   // quad
    const int r16    = lane & 15;   // A: m / B: n / C: col
    const int j0     = member * 16;

    // ---------- preload weights into VGPRs as B-fragments ----------
    // B[k][n]: n = lane&15, k = kk*32 + q*8 + e
    f16x8 bw[24];
    if (wave < 4) {
        const int col = wave * 512 + j0 + r16;
#pragma unroll
        for (int kk = 0; kk < 24; ++kk) {
            f16x8 v;
            const int kbase = kk * 32 + q * 8;
#pragma unroll
            for (int e = 0; e < 8; ++e) {
                const int k = kbase + e;
                const float w = (kk < 16) ? W_all[k * 2048 + col]
                                          : U_all[(k - 512) * 2048 + col];
                v[e] = (f16)w;
            }
            bw[kk] = v;
        }
    } else {
        const int col = j0 + r16;
#pragma unroll
        for (int kk = 0; kk < 16; ++kk) {
            f16x8 v;
            const int kbase = kk * 32 + q * 8;
#pragma unroll
            for (int e = 0; e < 8; ++e) v[e] = (f16)W_d[(kbase + e) * 512 + col];
            bw[kk] = v;
        }
#pragma unroll
        for (int kk = 16; kk < 24; ++kk) bw[kk] = bw[0];
    }

    // slice list for this wave (remote slices, round-robin over 5 waves)
    int sl[7];
    int ns = 0;
    for (int s = wave; s < 32; s += 5)
        if (s != member) sl[ns++] = s;

    // ---------- init LDS state ----------
    {
        uint4 z; z.x = z.y = z.z = z.w = 0u;
        uint4* a4 = (uint4*)A_sm;
        uint4* c4 = (uint4*)C_sm;
        for (int i = tid; i < 1024; i += 320) { a4[i] = z; c4[i] = z; }
        if (tid < 256) c_loc[tid] = 0.0f;
        if (tid < 64) {
            const int w = tid >> 4, n = tid & 15;
            const int col = w * 512 + j0 + n;
            bias_sm[w * 16 + n] = b_all[col] + b_u[col];
        } else if (tid < 80) {
            const int n = tid & 15;
            bias_sm[64 + n] = b_d[j0 + n];
        }
        if (tid < 16) len_sm[tid] = lens[grp * 16 + tid];
        // stage x(0) into A_sm kb 64..95
        for (int idx = tid; idx < 1024; idx += 320) {
            const int b = idx >> 6;
            const int kx0 = (idx & 63) << 2;
            const float4 v = *(const float4*)&inputs[(((size_t)(grp * 16 + b)) * S_ + 0) * IN_ + kx0];
            union { f16 h[4]; uint2 u; } p;
            p.h[0] = (f16)v.x; p.h[1] = (f16)v.y; p.h[2] = (f16)v.z; p.h[3] = (f16)v.w;
            const int kb = 64 + (kx0 >> 3), e = kx0 & 7;
            *(uint2*)&A_sm[(kb * 16 + b) * 8 + e] = p.u;
        }
    }
    __syncthreads();

    // per-group exchange buffer: 2 phases x 8192 qwords (64 KB per phase)
    unsigned long long* const hc_g = hcbuf + (size_t)grp * 2 * 8192;

    for (int t = 0; t < S_; ++t) {
        // ts(t) prefetch — overlaps the MFMA phase below
        float ts = 0.0f;
        if (tid < 256) {
            const int gb = grp * 16 + (tid >> 4);
            ts = tstamps[(size_t)gb * S_ + t];
        }

        // ---------- MFMA phase ----------
        f32x4 acc0 = {0.f, 0.f, 0.f, 0.f}, acc1 = {0.f, 0.f, 0.f, 0.f};
        if (wave < 4) {
            const f16* abase = &A_sm[(q * 16 + r16) * 8];
#pragma unroll
            for (int kk = 0; kk < 24; ++kk) {
                const f16x8 a = *(const f16x8*)(abase + kk * 512);
                if (kk & 1) acc1 = __builtin_amdgcn_mfma_f32_16x16x32_f16(a, bw[kk], acc1, 0, 0, 0);
                else        acc0 = __builtin_amdgcn_mfma_f32_16x16x32_f16(a, bw[kk], acc0, 0, 0, 0);
            }
        } else {
            const f16* abase = &C_sm[(q * 16 + r16) * 8];
#pragma unroll
            for (int kk = 0; kk < 16; ++kk) {
                const f16x8 a = *(const f16x8*)(abase + kk * 512);
                if (kk & 1) acc1 = __builtin_amdgcn_mfma_f32_16x16x32_f16(a, bw[kk], acc1, 0, 0, 0);
                else        acc0 = __builtin_amdgcn_mfma_f32_16x16x32_f16(a, bw[kk], acc0, 0, 0, 0);
            }
        }
        const f32x4 acc = acc0 + acc1;
        // C/D: col = lane&15, row = quad*4 + reg  (row = batch)
#pragma unroll
        for (int r = 0; r < 4; ++r)
            outs_sm[(wave * 16 + q * 4 + r) * 17 + r16] = acc[r];
        __syncthreads();   // B1: outs_sm produced; MFMA done reading A/C_sm

        // ---------- elementwise gates + tagged publish ----------
        if (tid < 256) {
            const int b = tid >> 4, jj = tid & 15;
            const int gb = grp * 16 + b;
            const float f  = outs_sm[(0 * 16 + b) * 17 + jj] + bias_sm[0  + jj];
            const float i_ = outs_sm[(1 * 16 + b) * 17 + jj] + bias_sm[16 + jj];
            const float o  = outs_sm[(2 * 16 + b) * 17 + jj] + bias_sm[32 + jj];
            const float ct = outs_sm[(3 * 16 + b) * 17 + jj] + bias_sm[48 + jj];
            const float d  = outs_sm[(4 * 16 + b) * 17 + jj] + bias_sm[64 + jj];
            const float gt = 1.0f / __logf(ECONST + ts);
            const float cs1   = tanh_f(d);
            const float cprev = c_loc[tid];
            const float cadj  = cprev - cs1 + cs1 * gt;
            const float cnew  = sigf(f) * cadj + sigf(i_) * tanh_f(ct);
            const float hnew  = sigf(o) * tanh_f(cnew);
            // publish FIRST — this store is the group-wide critical path.
            // qword = {tag=t+1, packed(h,c)}; self-validating, no flag needed.
            const unsigned long long qv =
                ((unsigned long long)(unsigned int)(t + 1) << 32) |
                (unsigned long long)pack_hc(hnew, cnew);
            __hip_atomic_store(hc_g + (size_t)(t & 1) * 8192 + member * 256 + tid, qv,
                               __ATOMIC_RELAXED, __HIP_MEMORY_SCOPE_AGENT);
            c_loc[tid] = cnew;
            const int col = j0 + jj;
            const int len = len_sm[b];
            out0[((size_t)gb * S_ + t) * H_ + col] = (t < len) ? hnew : 0.0f;
            if (t == len - 1) {
                out1[gb * H_ + col] = hnew;
                out2[gb * H_ + col] = cnew;
            }
            // own slice straight into LDS operands (never gathered)
            const int fi = ((col >> 3) * 16 + b) * 8 + (col & 7);
            ((f16*)A_sm)[fi] = (f16)hnew;
            ((f16*)C_sm)[fi] = (f16)cnew;
        }

        // compiler fence: publish stores may not sink below the poll loads
        // (deadlock guard; no instruction cost, HW needs no fence — each
        // qword is atomically self-consistent and tags are monotone).
        asm volatile("" ::: "memory");

        if (t < S_ - 1) {
            // issue x(t+1) loads now; latency hides under the poll window
            float4 xv[4];
            if (tid < 256) {
#pragma unroll
                for (int k2 = 0; k2 < 4; ++k2) {
                    const int idx = k2 * 256 + tid;
                    const int b = idx >> 6;
                    const int kx0 = (idx & 63) << 2;
                    xv[k2] = *(const float4*)&inputs[(((size_t)(grp * 16 + b)) * S_ + (t + 1)) * IN_ + kx0];
                }
            }

            // ---------- poll-gather: spin directly on tagged data ----------
            // slice layout: qword j = b*16 + c (c = local col). lane owns
            // j = 4*lane .. 4*lane+3  ->  same b, 4 consecutive cols.
            const unsigned long long* src = hc_g + (size_t)(t & 1) * 8192;
            const unsigned int tag = (unsigned int)(t + 1);
            const int jb = lane * 4;
            unsigned long long v[7][4];
            unsigned int pend = (1u << (4 * ns)) - 1u;
            do {
                // pass 1: issue all pending loads (batched, then one drain)
#pragma unroll
                for (int u = 0; u < 7; ++u) {
                    if (u < ns) {
                        const unsigned long long* sb = src + sl[u] * 256 + jb;
#pragma unroll
                        for (int k = 0; k < 4; ++k)
                            if ((pend >> (u * 4 + k)) & 1u)
                                v[u][k] = __hip_atomic_load(sb + k, __ATOMIC_RELAXED,
                                                            __HIP_MEMORY_SCOPE_AGENT);
                    }
                }
                // pass 2: validate tags
#pragma unroll
                for (int u = 0; u < 7; ++u) {
                    if (u < ns) {
#pragma unroll
                        for (int k = 0; k < 4; ++k)
                            if (((pend >> (u * 4 + k)) & 1u) &&
                                (unsigned int)(v[u][k] >> 32) == tag)
                                pend &= ~(1u << (u * 4 + k));
                    }
                }
            } while (__ballot(pend != 0u) != 0ull);

            // unpack: per slice 2x ds_write_b64 to A_sm + 2x... (1 uint2 each)
            const int ub  = lane >> 2;          // batch row
            const int uc4 = (lane & 3) * 4;     // local col base (0,4,8,12)
#pragma unroll
            for (int u = 0; u < 7; ++u) {
                if (u < ns) {
                    const int s = sl[u];
                    const unsigned int p0 = (unsigned int)v[u][0];
                    const unsigned int p1 = (unsigned int)v[u][1];
                    const unsigned int p2 = (unsigned int)v[u][2];
                    const unsigned int p3 = (unsigned int)v[u][3];
                    const int col = s * 16 + uc4;
                    const int fi  = ((col >> 3) * 16 + ub) * 8 + (col & 7);  // 8-aligned*2B
                    uint2 hp, cp;
                    hp.x = (p0 & 0xFFFFu) | (p1 << 16);
                    hp.y = (p2 & 0xFFFFu) | (p3 << 16);
                    cp.x = (p0 >> 16) | (p1 & 0xFFFF0000u);
                    cp.y = (p2 >> 16) | (p3 & 0xFFFF0000u);
                    *(uint2*)((f16*)A_sm + fi) = hp;
                    *(uint2*)((f16*)C_sm + fi) = cp;
                }
            }

            // stage x(t+1) into A_sm kb 64..95
            if (tid < 256) {
#pragma unroll
                for (int k2 = 0; k2 < 4; ++k2) {
                    const int idx = k2 * 256 + tid;
                    const int b = idx >> 6;
                    const int kx0 = (idx & 63) << 2;
                    union { f16 h[4]; uint2 u; } p;
                    p.h[0] = (f16)xv[k2].x; p.h[1] = (f16)xv[k2].y;
                    p.h[2] = (f16)xv[k2].z; p.h[3] = (f16)xv[k2].w;
                    const int kb = 64 + (kx0 >> 3), e = kx0 & 7;
                    *(uint2*)&A_sm[(kb * 16 + b) * 8 + e] = p.u;
                }
            }
            __syncthreads();   // B2: operands for step t+1 ready
        }
    }
}

extern "C" void kernel_launch(void* const* d_in, const int* in_sizes, int n_in,
                              void* d_out, int out_size, void* d_ws, size_t ws_size,
                              hipStream_t stream) {
    const float* inputs  = (const float*)d_in[0];
    const float* tstamps = (const float*)d_in[1];
    const int*   lens    = (const int*)d_in[2];
    const float* W_all   = (const float*)d_in[3];
    const float* b_all   = (const float*)d_in[4];
    const float* U_all   = (const float*)d_in[5];
    const float* b_u     = (const float*)d_in[6];
    const float* W_d     = (const float*)d_in[7];
    const float* b_d     = (const float*)d_in[8];

    float* out0 = (float*)d_out;                    // [64,1024,512]
    float* out1 = out0 + (size_t)64 * 1024 * 512;   // last_h [64,512]
    float* out2 = out1 + (size_t)64 * 512;          // last_c [64,512]

    // exchange buffer: 4 groups x 2 phases x 8192 qwords = 512 KB.
    // No memset needed: tags are compared for EQUALITY with t+1, so the
    // 0xAA..AA poison (or stale t-1 tags) simply fails the match and retries.
    unsigned long long* hcbuf = (unsigned long long*)d_ws;

    tlstm_scan<<<dim3(128), dim3(320), 0, stream>>>(
        inputs, tstamps, lens, W_all, b_all, U_all, b_u, W_d, b_d,
        out0, out1, out2, hcbuf);
}

// Round 2
// 4569.166 us; speedup vs baseline: 1.2778x; 1.2778x over previous
//
#include <hip/hip_runtime.h>

// TimeLSTM persistent-scan kernel for MI355X (gfx950), round 5.
// Grid: 128 blocks x 320 threads. grp = blockIdx&3 owns batches grp*16..+15;
// member = blockIdx>>2 owns columns member*16..+15 of each gate and of W_d.
// Weights live in VGPRs as f16 MFMA B-fragments for all 1024 steps.
//
// Round-5 changes (round-4 tag-in-data REVERTED — polling data words made the
// retry period a full gather-RT and cost +2.3us/step):
//  (a) x-projection offload: the 8 U_all@x MFMAs are h-independent; compute
//      them into carry regs (accx) during the comm window from a dedicated
//      double-buffered X_sm, so the gated MFMA phase is 16 MFMAs for ALL
//      waves (balanced) and x staging leaves the critical path.
//  (b) per-wave sub-flags: producer wave stores its 64 qwords -> wave-local
//      s_waitcnt vmcnt(0) -> sub-flag store (4 flags/slice). No block-wide
//      drain barrier before flags; flags fire as each wave's data lands.
//      out0/out1/out2 stores issue AFTER the flag (off the drain path).
// Protocol safety: monotone tags, >= compare, 2-phase data buffer, flags
// memset to 0 (ws poisoned 0xAA would false-pass >=). Max skew 1 step.

typedef _Float16 f16;
typedef _Float16 f16x8 __attribute__((ext_vector_type(8)));
typedef float f32x4 __attribute__((ext_vector_type(4)));

#define S_ 1024
#define IN_ 256
#define H_ 512
#define ECONST 2.718281828459045f

__device__ __forceinline__ float sigf(float x) { return 1.0f / (1.0f + __expf(-x)); }
__device__ __forceinline__ float tanh_f(float x) { return 1.0f - 2.0f / (__expf(2.0f * x) + 1.0f); }

__device__ __forceinline__ unsigned int pack_hc(float h, float c) {
    union { f16 f; unsigned short u; } ph, pc;
    ph.f = (f16)h; pc.f = (f16)c;
    return ((unsigned int)pc.u << 16) | (unsigned int)ph.u;
}

__launch_bounds__(320, 2)
__global__ void tlstm_scan(
    const float* __restrict__ inputs, const float* __restrict__ tstamps,
    const int* __restrict__ lens,
    const float* __restrict__ W_all, const float* __restrict__ b_all,
    const float* __restrict__ U_all, const float* __restrict__ b_u,
    const float* __restrict__ W_d, const float* __restrict__ b_d,
    float* __restrict__ out0, float* __restrict__ out1, float* __restrict__ out2,
    unsigned long long* __restrict__ hcbuf, unsigned int* __restrict__ flags)
{
    __shared__ __align__(16) f16 A_sm[64 * 16 * 8];     // 16 KB  (h operand)
    __shared__ __align__(16) f16 C_sm[64 * 16 * 8];     // 16 KB  (c operand)
    __shared__ __align__(16) f16 X_sm[2][32 * 16 * 8];  // 16 KB  (x dbuf)
    __shared__ float outs_sm[5 * 16 * 17];              // +1 pad on col
    __shared__ float c_loc[16 * 16];                    // fp32 c state (own cells)
    __shared__ float bias_sm[5 * 16];
    __shared__ int   len_sm[16];

    const int tid    = threadIdx.x;
    const int grp    = blockIdx.x & 3;
    const int member = blockIdx.x >> 2;
    const int wave   = tid >> 6;
    const int lane   = tid & 63;
    const int q      = lane >> 4;   // quad
    const int r16    = lane & 15;   // A: m / B: n / C: col
    const int j0     = member * 16;

    // ---------- preload weights into VGPRs as B-fragments ----------
    // B[k][n]: n = lane&15, k = kk*32 + q*8 + e
    f16x8 bw[24];
    if (wave < 4) {
        const int col = wave * 512 + j0 + r16;
#pragma unroll
        for (int kk = 0; kk < 24; ++kk) {
            f16x8 v;
            const int kbase = kk * 32 + q * 8;
#pragma unroll
            for (int e = 0; e < 8; ++e) {
                const int k = kbase + e;
                const float w = (kk < 16) ? W_all[k * 2048 + col]
                                          : U_all[(k - 512) * 2048 + col];
                v[e] = (f16)w;
            }
            bw[kk] = v;
        }
    } else {
        const int col = j0 + r16;
#pragma unroll
        for (int kk = 0; kk < 16; ++kk) {
            f16x8 v;
            const int kbase = kk * 32 + q * 8;
#pragma unroll
            for (int e = 0; e < 8; ++e) v[e] = (f16)W_d[(kbase + e) * 512 + col];
            bw[kk] = v;
        }
#pragma unroll
        for (int kk = 16; kk < 24; ++kk) bw[kk] = bw[0];
    }

    // slice list for this wave (remote slices, round-robin over 5 waves)
    int sl[7];
    int ns = 0;
    for (int s = wave; s < 32; s += 5)
        if (s != member) sl[ns++] = s;

    // ---------- init LDS state ----------
    {
        uint4 z; z.x = z.y = z.z = z.w = 0u;
        uint4* a4 = (uint4*)A_sm;
        uint4* c4 = (uint4*)C_sm;
        for (int i = tid; i < 1024; i += 320) { a4[i] = z; c4[i] = z; }
        if (tid < 256) c_loc[tid] = 0.0f;
        if (tid < 64) {
            const int w = tid >> 4, n = tid & 15;
            const int col = w * 512 + j0 + n;
            bias_sm[w * 16 + n] = b_all[col] + b_u[col];
        } else if (tid < 80) {
            const int n = tid & 15;
            bias_sm[64 + n] = b_d[j0 + n];
        }
        if (tid < 16) len_sm[tid] = lens[grp * 16 + tid];
        // stage x(0) into X_sm[0]
        for (int idx = tid; idx < 1024; idx += 320) {
            const int b = idx >> 6;
            const int kx0 = (idx & 63) << 2;
            const float4 v = *(const float4*)&inputs[(((size_t)(grp * 16 + b)) * S_ + 0) * IN_ + kx0];
            union { f16 h[4]; uint2 u; } p;
            p.h[0] = (f16)v.x; p.h[1] = (f16)v.y; p.h[2] = (f16)v.z; p.h[3] = (f16)v.w;
            const int kb = kx0 >> 3, e = kx0 & 7;
            *(uint2*)&X_sm[0][(kb * 16 + b) * 8 + e] = p.u;
        }
    }
    __syncthreads();

    // ---------- pre-loop: accx(0) from X_sm[0]; stage x(1) -> X_sm[1] ----------
    f32x4 accx0 = {0.f, 0.f, 0.f, 0.f}, accx1 = {0.f, 0.f, 0.f, 0.f};
    {
        float4 xv1[4];
        if (tid < 256) {
#pragma unroll
            for (int k2 = 0; k2 < 4; ++k2) {
                const int idx = k2 * 256 + tid;
                const int b = idx >> 6;
                const int kx0 = (idx & 63) << 2;
                xv1[k2] = *(const float4*)&inputs[(((size_t)(grp * 16 + b)) * S_ + 1) * IN_ + kx0];
            }
        }
        if (wave < 4) {
            const f16* xb = &X_sm[0][(q * 16 + r16) * 8];
#pragma unroll
            for (int kx = 0; kx < 8; ++kx) {
                const f16x8 a = *(const f16x8*)(xb + kx * 512);
                if (kx & 1) accx1 = __builtin_amdgcn_mfma_f32_16x16x32_f16(a, bw[16 + kx], accx1, 0, 0, 0);
                else        accx0 = __builtin_amdgcn_mfma_f32_16x16x32_f16(a, bw[16 + kx], accx0, 0, 0, 0);
            }
        }
        if (tid < 256) {
#pragma unroll
            for (int k2 = 0; k2 < 4; ++k2) {
                const int idx = k2 * 256 + tid;
                const int b = idx >> 6;
                const int kx0 = (idx & 63) << 2;
                union { f16 h[4]; uint2 u; } p;
                p.h[0] = (f16)xv1[k2].x; p.h[1] = (f16)xv1[k2].y;
                p.h[2] = (f16)xv1[k2].z; p.h[3] = (f16)xv1[k2].w;
                const int kb = kx0 >> 3, e = kx0 & 7;
                *(uint2*)&X_sm[1][(kb * 16 + b) * 8 + e] = p.u;
            }
        }
    }
    __syncthreads();

    // per-group exchange buffer: 2 phases x 4096 qwords (32 KB per phase)
    unsigned long long* const hc_g = hcbuf + (size_t)grp * 2 * 4096;
    unsigned int* const flg = flags + grp * 128;   // 32 slices x 4 sub-flags

    for (int t = 0; t < S_; ++t) {
        // ts(t) prefetch — overlaps the MFMA phase below
        float ts = 0.0f;
        if (tid < 256) {
            const int gb = grp * 16 + (tid >> 4);
            ts = tstamps[(size_t)gb * S_ + t];
        }

        // ---------- gated MFMA phase: 16 MFMAs per wave (balanced) ----------
        f32x4 acc0, acc1;
        if (wave < 4) {
            acc0 = accx0; acc1 = accx1;   // x contribution, precomputed
            const f16* abase = &A_sm[(q * 16 + r16) * 8];
#pragma unroll
            for (int kk = 0; kk < 16; ++kk) {
                const f16x8 a = *(const f16x8*)(abase + kk * 512);
                if (kk & 1) acc1 = __builtin_amdgcn_mfma_f32_16x16x32_f16(a, bw[kk], acc1, 0, 0, 0);
                else        acc0 = __builtin_amdgcn_mfma_f32_16x16x32_f16(a, bw[kk], acc0, 0, 0, 0);
            }
        } else {
            acc0 = (f32x4){0.f, 0.f, 0.f, 0.f}; acc1 = acc0;
            const f16* abase = &C_sm[(q * 16 + r16) * 8];
#pragma unroll
            for (int kk = 0; kk < 16; ++kk) {
                const f16x8 a = *(const f16x8*)(abase + kk * 512);
                if (kk & 1) acc1 = __builtin_amdgcn_mfma_f32_16x16x32_f16(a, bw[kk], acc1, 0, 0, 0);
                else        acc0 = __builtin_amdgcn_mfma_f32_16x16x32_f16(a, bw[kk], acc0, 0, 0, 0);
            }
        }
        const f32x4 acc = acc0 + acc1;
        // C/D: col = lane&15, row = quad*4 + reg  (row = batch)
#pragma unroll
        for (int r = 0; r < 4; ++r)
            outs_sm[(wave * 16 + q * 4 + r) * 17 + r16] = acc[r];
        __syncthreads();   // B1: outs_sm produced; MFMA done reading A/C_sm

        // ---------- elementwise + publish + per-wave sub-flag ----------
        if (tid < 256) {
            const int b = tid >> 4, jj = tid & 15;
            const int gb = grp * 16 + b;
            const float f  = outs_sm[(0 * 16 + b) * 17 + jj] + bias_sm[0  + jj];
            const float i_ = outs_sm[(1 * 16 + b) * 17 + jj] + bias_sm[16 + jj];
            const float o  = outs_sm[(2 * 16 + b) * 17 + jj] + bias_sm[32 + jj];
            const float ct = outs_sm[(3 * 16 + b) * 17 + jj] + bias_sm[48 + jj];
            const float d  = outs_sm[(4 * 16 + b) * 17 + jj] + bias_sm[64 + jj];
            const float gt = 1.0f / __logf(ECONST + ts);
            const float cs1   = tanh_f(d);
            const float cprev = c_loc[tid];
            const float cadj  = cprev - cs1 + cs1 * gt;
            const float cnew  = sigf(f) * cadj + sigf(i_) * tanh_f(ct);
            const float hnew  = sigf(o) * tanh_f(cnew);
            c_loc[tid] = cnew;
            // publish FIRST — group-wide critical path
            unsigned int* dw = (unsigned int*)(hc_g + (size_t)(t & 1) * 4096);
            __hip_atomic_store(dw + member * 256 + tid, pack_hc(hnew, cnew),
                               __ATOMIC_RELAXED, __HIP_MEMORY_SCOPE_AGENT);
            // own slice straight into LDS operands (lgkm — not on the drain)
            const int col = j0 + jj;
            const int fi = ((col >> 3) * 16 + b) * 8 + (col & 7);
            ((f16*)A_sm)[fi] = (f16)hnew;
            ((f16*)C_sm)[fi] = (f16)cnew;
            // wave-local drain: only THIS wave's publish stores gate the flag
            asm volatile("s_waitcnt vmcnt(0)" ::: "memory");
            if ((tid & 63) == 0)
                __hip_atomic_store(&flg[member * 4 + wave], (unsigned int)(t + 1),
                                   __ATOMIC_RELAXED, __HIP_MEMORY_SCOPE_AGENT);
            // output stores AFTER the flag — off the critical path
            const int len = len_sm[b];
            out0[((size_t)gb * S_ + t) * H_ + col] = (t < len) ? hnew : 0.0f;
            if (t == len - 1) {
                out1[gb * H_ + col] = hnew;
                out2[gb * H_ + col] = cnew;
            }
        }
        asm volatile("" ::: "memory");

        if (t < S_ - 1) {
            // ---------- comm window: x-MFMA for t+1 overlaps flag RT ----------
            if (wave < 4) {
                const f16* xb = &X_sm[(t + 1) & 1][(q * 16 + r16) * 8];
                f32x4 ax0 = {0.f, 0.f, 0.f, 0.f}, ax1 = {0.f, 0.f, 0.f, 0.f};
#pragma unroll
                for (int kx = 0; kx < 8; ++kx) {
                    const f16x8 a = *(const f16x8*)(xb + kx * 512);
                    if (kx & 1) ax1 = __builtin_amdgcn_mfma_f32_16x16x32_f16(a, bw[16 + kx], ax1, 0, 0, 0);
                    else        ax0 = __builtin_amdgcn_mfma_f32_16x16x32_f16(a, bw[16 + kx], ax0, 0, 0, 0);
                }
                accx0 = ax0; accx1 = ax1;
            }

            // issue x(t+2) loads; latency hides under poll/gather
            const bool ldx = (t + 2 < S_);
            float4 xv[4];
            if (ldx && tid < 256) {
#pragma unroll
                for (int k2 = 0; k2 < 4; ++k2) {
                    const int idx = k2 * 256 + tid;
                    const int b = idx >> 6;
                    const int kx0 = (idx & 63) << 2;
                    xv[k2] = *(const float4*)&inputs[(((size_t)(grp * 16 + b)) * S_ + (t + 2)) * IN_ + kx0];
                }
            }

            // lane-parallel sub-flag wait: 4 flags per remote slice
            const unsigned int tag = (unsigned int)(t + 1);
            for (;;) {
                unsigned int fl = tag;
                if (lane < 4 * ns)
                    fl = __hip_atomic_load(&flg[sl[lane >> 2] * 4 + (lane & 3)],
                                           __ATOMIC_RELAXED, __HIP_MEMORY_SCOPE_AGENT);
                if (__ballot(fl >= tag) == ~0ull) break;
            }

            // batched gather: 2 qwords per lane per slice, single wait
            const unsigned long long* src = hc_g + (size_t)(t & 1) * 4096;
            unsigned long long v[7][2];
#pragma unroll
            for (int u = 0; u < 7; ++u) {
                if (u < ns) {
                    const int s = sl[u];
                    v[u][0] = __hip_atomic_load(src + s * 128 + lane,
                                                __ATOMIC_RELAXED, __HIP_MEMORY_SCOPE_AGENT);
                    v[u][1] = __hip_atomic_load(src + s * 128 + 64 + lane,
                                                __ATOMIC_RELAXED, __HIP_MEMORY_SCOPE_AGENT);
                }
            }
#pragma unroll
            for (int u = 0; u < 7; ++u) {
                if (u < ns) {
                    const int s = sl[u];
#pragma unroll
                    for (int dd = 0; dd < 2; ++dd) {
                        const int j = dd * 64 + lane;       // qword index in slice
                        const int b = j >> 3;
                        const int colL = (j & 7) * 2;
                        const int col = s * 16 + colL;
                        const unsigned long long qv = v[u][dd];
                        const unsigned int d0 = (unsigned int)qv;
                        const unsigned int d1 = (unsigned int)(qv >> 32);
                        const unsigned int hpair = (d0 & 0xFFFFu) | (d1 << 16);
                        const unsigned int cpair = (d0 >> 16) | (d1 & 0xFFFF0000u);
                        const int fi = ((col >> 3) * 16 + b) * 8 + (col & 7);
                        *(unsigned int*)((f16*)A_sm + fi) = hpair;
                        *(unsigned int*)((f16*)C_sm + fi) = cpair;
                    }
                }
            }

            // stage x(t+2) into X_sm[t&1] (that buffer's x(t) consumed at t-1)
            if (ldx && tid < 256) {
#pragma unroll
                for (int k2 = 0; k2 < 4; ++k2) {
                    const int idx = k2 * 256 + tid;
                    const int b = idx >> 6;
                    const int kx0 = (idx & 63) << 2;
                    union { f16 h[4]; uint2 u; } p;
                    p.h[0] = (f16)xv[k2].x; p.h[1] = (f16)xv[k2].y;
                    p.h[2] = (f16)xv[k2].z; p.h[3] = (f16)xv[k2].w;
                    const int kb = kx0 >> 3, e = kx0 & 7;
                    *(uint2*)&X_sm[t & 1][(kb * 16 + b) * 8 + e] = p.u;
                }
            }
            __syncthreads();   // B2: operands for step t+1 ready
        }
    }
}

extern "C" void kernel_launch(void* const* d_in, const int* in_sizes, int n_in,
                              void* d_out, int out_size, void* d_ws, size_t ws_size,
                              hipStream_t stream) {
    const float* inputs  = (const float*)d_in[0];
    const float* tstamps = (const float*)d_in[1];
    const int*   lens    = (const int*)d_in[2];
    const float* W_all   = (const float*)d_in[3];
    const float* b_all   = (const float*)d_in[4];
    const float* U_all   = (const float*)d_in[5];
    const float* b_u     = (const float*)d_in[6];
    const float* W_d     = (const float*)d_in[7];
    const float* b_d     = (const float*)d_in[8];

    float* out0 = (float*)d_out;                    // [64,1024,512]
    float* out1 = out0 + (size_t)64 * 1024 * 512;   // last_h [64,512]
    float* out2 = out1 + (size_t)64 * 512;          // last_c [64,512]

    char* ws = (char*)d_ws;
    unsigned int* flags = (unsigned int*)ws;                       // 4 grp * 128 dwords
    unsigned long long* hcbuf = (unsigned long long*)(ws + 2048);  // 4 grp * 2 * 32KB

    // flags must start at 0 every call (ws is poisoned 0xAA; >= compare)
    hipMemsetAsync(ws, 0, 2048, stream);

    tlstm_scan<<<dim3(128), dim3(320), 0, stream>>>(
        inputs, tstamps, lens, W_all, b_all, U_all, b_u, W_d, b_d,
        out0, out1, out2, hcbuf, flags);
}